// Round 3
// baseline (206.505 us; speedup 1.0000x reference)
//
#include <hip/hip_runtime.h>
#include <hip/hip_bf16.h>

#define DIN 256
#define DOUT 128
#define NB 64

using short8  = __attribute__((ext_vector_type(8))) short;
using floatx4 = __attribute__((ext_vector_type(4))) float;

__device__ __forceinline__ unsigned short f2bf(float f) {
    union { float f; unsigned u; } x; x.f = f;
    unsigned u = x.u;
    unsigned r = u + 0x7fffu + ((u >> 16) & 1u);   // round-to-nearest-even
    return (unsigned short)(r >> 16);
}

// Bfrag in MFMA-fragment order, lane-major (fully coalesced):
//   Bfrag[((wt*8 + ks)*64 + lane)*8 + j] = bf16(W0[(ks*32 + (lane>>4)*8 + j)][wt*16 + (lane&15)])
__global__ void w0_pack_kernel(const float* __restrict__ W0,
                               unsigned short* __restrict__ Bfrag) {
    int e = blockIdx.x * blockDim.x + threadIdx.x;   // 32768 elements
    int j  = e & 7;
    int l  = (e >> 3) & 63;
    int ks = (e >> 9) & 7;
    int wt = e >> 12;
    int k = ks * 32 + (l >> 4) * 8 + j;
    int c = wt * 16 + (l & 15);
    Bfrag[e] = f2bf(W0[k * DOUT + c]);
}

__global__ __launch_bounds__(512, 4) void fused_embed_kernel(
    const float* __restrict__ feat0,
    const float* __restrict__ emb_table,
    const unsigned short* __restrict__ Bfrag,
    const int* __restrict__ node_ids,
    const int* __restrict__ node_tids,
    const int* __restrict__ type_ids,
    float* __restrict__ out,
    int n, int ntiles, int tpb)
{
    __shared__ unsigned short sA[2][NB * DIN];   // 2 x 32 KB, XOR-swizzled rows
    __shared__ unsigned char  sFeat[2][NB];

    const int t  = threadIdx.x;
    const int w  = t >> 6;       // wave 0..7 = output col tile
    const int l  = t & 63;
    const int m  = t >> 3;       // staging: node in tile 0..63
    const int p  = t & 7;        // staging: part 0..7
    const int lr = l & 15;
    const int kg = l >> 4;

    const int t0 = blockIdx.x * tpb;
    const int t1 = (t0 + tpb < ntiles) ? (t0 + tpb) : ntiles;
    if (t0 >= t1) return;

    // ---- B fragments: load ONCE per persistent block ----
    short8 bf[8];
    {
        const short8* bsrc = reinterpret_cast<const short8*>(Bfrag);
        #pragma unroll
        for (int ks = 0; ks < 8; ++ks)
            bf[ks] = bsrc[(w * 8 + ks) * 64 + l];
    }

    // index regs: A = tile being gathered this iter (t+1), B = prefetch (t+2)
    int tidA = -1, gtA = 0, gnA = 0;
    int tidB = -1, gtB = 0, gnB = 0;
    float4 v[8];

    auto loadIdx = [&](int tt, int& tid, int& gt, int& gn) {
        const int i = tt * NB + m;
        if (i < n) { tid = node_tids[i]; gt = type_ids[i]; gn = node_ids[i]; }
        else tid = -1;
    };
    auto issueGather = [&](int tid, int gt, int gn) {
        if (tid == 0) {
            const float* src = feat0 + (long long)gt * DIN;
            #pragma unroll
            for (int j = 0; j < 8; ++j)
                v[j] = *reinterpret_cast<const float4*>(src + j * 32 + p * 4);
        } else if (tid == 1) {
            const float4* src = reinterpret_cast<const float4*>(
                emb_table + (long long)gn * DOUT);
            #pragma unroll
            for (int j = 0; j < 4; ++j) v[j] = src[p + j * 8];
        }
    };
    auto commit = [&](int buf, int tt, int tid) {
        if (tid == 0) {
            char* basep = reinterpret_cast<char*>(&sA[buf][0]);
            #pragma unroll
            for (int j = 0; j < 8; ++j) {
                const int k = j * 32 + p * 4;
                ushort4 pk;
                pk.x = f2bf(v[j].x); pk.y = f2bf(v[j].y);
                pk.z = f2bf(v[j].z); pk.w = f2bf(v[j].w);
                const unsigned addr =
                    (unsigned)(m * 512 + k * 2) ^ ((unsigned)(m & 7) << 4);
                *reinterpret_cast<ushort4*>(basep + addr) = pk;
            }
        } else if (tid == 1) {
            const int i = tt * NB + m;
            float4* dst = reinterpret_cast<float4*>(out + (long long)i * DOUT);
            #pragma unroll
            for (int j = 0; j < 4; ++j) dst[p + j * 8] = v[j];
        }
    };

    // ---- prologue: stage tile t0 into buf 0 ----
    loadIdx(t0, tidA, gtA, gnA);
    if (t0 + 1 < t1) loadIdx(t0 + 1, tidB, gtB, gnB);
    issueGather(tidA, gtA, gnA);
    if (p == 0) sFeat[0][m] = (tidA == 0) ? 1 : 0;
    commit(0, t0, tidA);
    tidA = tidB; gtA = gtB; gnA = gnB;
    __syncthreads();

    // ---- main pipeline: 1 barrier per tile ----
    for (int tt = t0; tt < t1; ++tt) {
        const int cur = (tt - t0) & 1;
        const int nxt = cur ^ 1;
        const bool hasNext = (tt + 1 < t1);

        // 1. issue gathers for tile tt+1 (async, consumed after MFMA)
        if (hasNext) {
            issueGather(tidA, gtA, gnA);
            if (p == 0) sFeat[nxt][m] = (tidA == 0) ? 1 : 0;
        }
        // 2. prefetch indices for tile tt+2
        if (tt + 2 < t1) loadIdx(tt + 2, tidB, gtB, gnB); else tidB = -1;

        // 3. MFMA on buf[cur]
        floatx4 acc[4];
        #pragma unroll
        for (int rt = 0; rt < 4; ++rt) acc[rt] = (floatx4){0.f, 0.f, 0.f, 0.f};
        const char* basep = reinterpret_cast<const char*>(&sA[cur][0]);
        #pragma unroll
        for (int ks = 0; ks < 8; ++ks) {
            #pragma unroll
            for (int rt = 0; rt < 4; ++rt) {
                const int row = rt * 16 + lr;
                const unsigned aaddr =
                    (unsigned)(row * 512 + ks * 64 + kg * 16) ^ ((unsigned)(row & 7) << 4);
                const short8 af = *reinterpret_cast<const short8*>(basep + aaddr);
                acc[rt] = __builtin_amdgcn_mfma_f32_16x16x32_bf16(af, bf[ks], acc[rt], 0, 0, 0);
            }
        }

        // 4. convert + commit tile tt+1 (vmcnt wait hidden under MFMA issue)
        if (hasNext) commit(nxt, tt + 1, tidA);

        // 5. pre-read store predicates for THIS tile
        bool ok[4];
        #pragma unroll
        for (int r = 0; r < 4; ++r) ok[r] = sFeat[cur][kg * 4 + r] != 0
                                            || false;   // placeholder, fixed below
        // (re-read correctly per row-tile below)
        #pragma unroll
        for (int r = 0; r < 4; ++r) ok[r] = false;
        unsigned char okb[16];
        #pragma unroll
        for (int rt = 0; rt < 4; ++rt)
            #pragma unroll
            for (int r = 0; r < 4; ++r)
                okb[rt * 4 + r] = sFeat[cur][rt * 16 + kg * 4 + r];

        __syncthreads();

        // 6. acc stores AFTER the barrier: the pre-barrier vmcnt(0) drain
        //    never waits on them; they overlap next iter's gathers.
        const int col  = w * 16 + lr;
        const int base = tt * NB;
        #pragma unroll
        for (int rt = 0; rt < 4; ++rt) {
            #pragma unroll
            for (int r = 0; r < 4; ++r) {
                const int row = rt * 16 + kg * 4 + r;
                if (okb[rt * 4 + r])
                    out[(long long)(base + row) * DOUT + col] = acc[rt][r];
            }
        }

        tidA = tidB; gtA = gtB; gnA = gnB;
    }
}

extern "C" void kernel_launch(void* const* d_in, const int* in_sizes, int n_in,
                              void* d_out, int out_size, void* d_ws, size_t ws_size,
                              hipStream_t stream) {
    const float* feat0      = (const float*)d_in[0];
    const float* W0         = (const float*)d_in[1];
    const float* emb_table  = (const float*)d_in[2];
    const int*   node_ids   = (const int*)d_in[3];
    const int*   node_tids  = (const int*)d_in[4];
    const int*   type_ids   = (const int*)d_in[5];
    float*       out        = (float*)d_out;
    const int n = in_sizes[3];                      // N = 500000

    unsigned short* Bfrag = (unsigned short*)d_ws;  // 64 KB in workspace

    hipLaunchKernelGGL(w0_pack_kernel, dim3((DIN * DOUT) / 256), dim3(256),
                       0, stream, W0, Bfrag);

    const int ntiles = (n + NB - 1) / NB;           // 7813
    const int grid   = 512;                         // 2 blocks/CU, persistent
    const int tpb    = (ntiles + grid - 1) / grid;  // 16
    hipLaunchKernelGGL(fused_embed_kernel, dim3(grid), dim3(512), 0, stream,
                       feat0, emb_table, Bfrag, node_ids, node_tids, type_ids,
                       out, n, ntiles, tpb);
}

// Round 4
// 182.234 us; speedup vs baseline: 1.1332x; 1.1332x over previous
//
#include <hip/hip_runtime.h>
#include <hip/hip_bf16.h>

#define DIN 256
#define DOUT 128

using short8  = __attribute__((ext_vector_type(8))) short;
using floatx4 = __attribute__((ext_vector_type(4))) float;

__device__ __forceinline__ unsigned short f2bf(float f) {
    union { float f; unsigned u; } x; x.f = f;
    unsigned u = x.u;
    unsigned r = u + 0x7fffu + ((u >> 16) & 1u);   // round-to-nearest-even
    return (unsigned short)(r >> 16);
}

// Bfrag in MFMA-fragment order, lane-major (verified in R2):
//   Bfrag[((ct*8 + ks)*64 + lane)*8 + j] = bf16(W0[(ks*32 + (lane>>4)*8 + j)][ct*16 + (lane&15)])
__global__ void w0_pack_kernel(const float* __restrict__ W0,
                               unsigned short* __restrict__ Bfrag) {
    int e = blockIdx.x * blockDim.x + threadIdx.x;   // 32768 elements
    int j  = e & 7;
    int l  = (e >> 3) & 63;
    int ks = (e >> 9) & 7;
    int ct = e >> 12;
    int k = ks * 32 + (l >> 4) * 8 + j;
    int c = ct * 16 + (l & 15);
    Bfrag[e] = f2bf(W0[k * DOUT + c]);
}

// 512 threads = 8 waves; each wave owns 16 nodes x all 128 cols.
// B (64KB) staged to LDS once; after that ZERO barriers — waves are
// fully independent latency streams.
__global__ __launch_bounds__(512, 4) void fused_embed_kernel(
    const float* __restrict__ feat0,
    const float* __restrict__ emb_table,
    const unsigned short* __restrict__ Bfrag,
    const int* __restrict__ node_ids,
    const int* __restrict__ node_tids,
    const int* __restrict__ type_ids,
    float* __restrict__ out,
    int n)
{
    __shared__ short8 sB[4096];   // [ct][ks][lane] = 64 KB, linear copy of Bfrag

    const int t = threadIdx.x;
    const int w = t >> 6;         // wave 0..7
    const int l = t & 63;
    const int lr = l & 15;        // A row within wave tile / D col index
    const int kg = l >> 4;        // k-group 0..3 / D row group

    // ---- stage B once (coalesced 64KB copy), single barrier ----
    {
        const short8* src = reinterpret_cast<const short8*>(Bfrag);
        #pragma unroll
        for (int j = 0; j < 8; ++j) sB[t + j * 512] = src[t + j * 512];
    }

    // ---- per-wave indices: lane lr -> node nodebase+lr (kg groups hold copies)
    const long long nodebase = (long long)blockIdx.x * 128 + w * 16;
    const long long myrow = nodebase + lr;
    int tid = 1, gt = 0, gn = 0;
    if (myrow < n) {
        tid = node_tids[myrow];
        gt  = type_ids[myrow];
        gn  = node_ids[myrow];
    }

    __syncthreads();   // sB ready (index loads overlapped the copy)

    // ---- MFMA: A fragments straight from global, B from LDS ----
    floatx4 acc[8];
    #pragma unroll
    for (int ct = 0; ct < 8; ++ct) acc[ct] = (floatx4){0.f, 0.f, 0.f, 0.f};

    // lane(lr,kg) feeds A[row=lr][k = ks*32 + kg*8 .. +8) = 32B at
    // feat0[gt] + ks*128 + kg*32  (rows 128B-aligned -> clean 64B lines)
    const float4* arow = reinterpret_cast<const float4*>(
        feat0 + (long long)gt * DIN) + kg * 2;
    #pragma unroll
    for (int ks = 0; ks < 8; ++ks) {
        const float4 a0 = arow[ks * 8];
        const float4 a1 = arow[ks * 8 + 1];
        short8 af;
        af[0] = (short)f2bf(a0.x); af[1] = (short)f2bf(a0.y);
        af[2] = (short)f2bf(a0.z); af[3] = (short)f2bf(a0.w);
        af[4] = (short)f2bf(a1.x); af[5] = (short)f2bf(a1.y);
        af[6] = (short)f2bf(a1.z); af[7] = (short)f2bf(a1.w);
        #pragma unroll
        for (int ct = 0; ct < 8; ++ct)
            acc[ct] = __builtin_amdgcn_mfma_f32_16x16x32_bf16(
                af, sB[(ct * 8 + ks) * 64 + l], acc[ct], 0, 0, 0);
    }

    // ---- store projected rows (D: row = kg*4+r, col = ct*16+lr) ----
    #pragma unroll
    for (int r = 0; r < 4; ++r) {
        const int row   = kg * 4 + r;
        const int t_r   = __shfl(tid, row);       // lane 'row' holds that node's tid
        const long long node = nodebase + row;
        if (t_r == 0 && node < n) {
            float* orow = out + node * DOUT;
            #pragma unroll
            for (int ct = 0; ct < 8; ++ct)
                orow[ct * 16 + lr] = acc[ct][r];
        }
    }

    // ---- featureless rows: wave-local copy, 4 lanes per row ----
    {
        const int crow = l >> 2;                  // 0..15
        const int csub = l & 3;
        const int t_c  = __shfl(tid, crow);
        const int gn_c = __shfl(gn, crow);
        const long long cnode = nodebase + crow;
        if (t_c == 1 && cnode < n) {
            const float4* src = reinterpret_cast<const float4*>(
                emb_table + (long long)gn_c * DOUT);
            float4* dst = reinterpret_cast<float4*>(out + cnode * DOUT);
            #pragma unroll
            for (int j = 0; j < 8; ++j) dst[csub + j * 4] = src[csub + j * 4];
        }
    }
}

extern "C" void kernel_launch(void* const* d_in, const int* in_sizes, int n_in,
                              void* d_out, int out_size, void* d_ws, size_t ws_size,
                              hipStream_t stream) {
    const float* feat0      = (const float*)d_in[0];
    const float* W0         = (const float*)d_in[1];
    const float* emb_table  = (const float*)d_in[2];
    const int*   node_ids   = (const int*)d_in[3];
    const int*   node_tids  = (const int*)d_in[4];
    const int*   type_ids   = (const int*)d_in[5];
    float*       out        = (float*)d_out;
    const int n = in_sizes[3];                      // N = 500000

    unsigned short* Bfrag = (unsigned short*)d_ws;  // 64 KB in workspace

    hipLaunchKernelGGL(w0_pack_kernel, dim3((DIN * DOUT) / 256), dim3(256),
                       0, stream, W0, Bfrag);

    const int grid = (n + 127) / 128;               // 128 nodes per block
    hipLaunchKernelGGL(fused_embed_kernel, dim3(grid), dim3(512), 0, stream,
                       feat0, emb_table, Bfrag, node_ids, node_tids, type_ids,
                       out, n);
}

// Round 5
// 154.422 us; speedup vs baseline: 1.3373x; 1.1801x over previous
//
#include <hip/hip_runtime.h>
#include <hip/hip_bf16.h>

#define DIN 256
#define DOUT 128

using short8  = __attribute__((ext_vector_type(8))) short;
using floatx4 = __attribute__((ext_vector_type(4))) float;

__device__ __forceinline__ unsigned short f2bf(float f) {
    union { float f; unsigned u; } x; x.f = f;
    unsigned u = x.u;
    unsigned r = u + 0x7fffu + ((u >> 16) & 1u);   // round-to-nearest-even
    return (unsigned short)(r >> 16);
}

// Bfrag in MFMA-fragment order, lane-major (verified R2/R4):
//   Bfrag[((ct*8 + ks)*64 + lane)*8 + j] = bf16(W0[(ks*32 + (lane>>4)*8 + j)][ct*16 + (lane&15)])
__global__ void w0_pack_kernel(const float* __restrict__ W0,
                               unsigned short* __restrict__ Bfrag) {
    int e = blockIdx.x * blockDim.x + threadIdx.x;   // 32768 elements
    int j  = e & 7;
    int l  = (e >> 3) & 63;
    int ks = (e >> 9) & 7;
    int ct = e >> 12;
    int k = ks * 32 + (l >> 4) * 8 + j;
    int c = ct * 16 + (l & 15);
    Bfrag[e] = f2bf(W0[k * DOUT + c]);
}

// 512 threads = 8 waves; each wave owns 16 nodes x all 128 cols.
// One barrier per block (B-stage); afterwards waves are independent
// latency streams with 16 hoisted A-loads + 8 emb-loads in flight.
__global__ __launch_bounds__(512, 2) void fused_embed_kernel(
    const float* __restrict__ feat0,
    const float* __restrict__ emb_table,
    const unsigned short* __restrict__ Bfrag,
    const int* __restrict__ node_ids,
    const int* __restrict__ node_tids,
    const int* __restrict__ type_ids,
    float* __restrict__ out,
    int n)
{
    __shared__ short8 sB[4096];   // [ct][ks][lane] = 64 KB

    const int t  = threadIdx.x;
    const int w  = t >> 6;        // wave 0..7
    const int l  = t & 63;
    const int lr = l & 15;        // A row in wave tile / D col
    const int kg = l >> 4;        // k-group / D row group

    // ---- 1. stage B (reg-staged coalesced copy) ----
    {
        const short8* src = reinterpret_cast<const short8*>(Bfrag);
        short8 tmp[8];
        #pragma unroll
        for (int j = 0; j < 8; ++j) tmp[j] = src[t + j * 512];
        #pragma unroll
        for (int j = 0; j < 8; ++j) sB[t + j * 512] = tmp[j];
    }

    // ---- 2. indices (4x redundant across kg groups; broadcast-cached) ----
    const long long nodebase = (long long)blockIdx.x * 128 + w * 16;
    const long long myrow = nodebase + lr;
    int tid = 1, gt = 0, gn = 0;
    if (myrow < n) {
        tid = node_tids[myrow];
        gt  = type_ids[myrow];
        gn  = node_ids[myrow];
    }

    // ---- 3. the ONLY barrier: drains B-stage (+idx loads, needed anyway) --
    __syncthreads();

    // ---- 4. hoist all 16 A-loads; featureless lanes hit row 0 (L1 dedup) --
    const bool featured = (tid == 0);
    const int  gts = featured ? gt : 0;
    const float4* arow = reinterpret_cast<const float4*>(
        feat0 + (long long)gts * DIN) + kg * 2;
    float4 av[16];
    #pragma unroll
    for (int ks = 0; ks < 8; ++ks) {
        av[2 * ks]     = arow[ks * 8];
        av[2 * ks + 1] = arow[ks * 8 + 1];
    }

    // ---- 5. emb-copy loads in flight too (4 lanes per row) ----
    const int crow = l >> 2;
    const int csub = l & 3;
    const int t_c  = __shfl(tid, crow);
    const int gn_c = __shfl(gn, crow);
    const long long cnode = nodebase + crow;
    const bool copyrow = (t_c == 1) && (cnode < n);
    const int  gns = copyrow ? gn_c : 0;
    const float4* esrc = reinterpret_cast<const float4*>(
        emb_table + (long long)gns * DOUT);
    float4 ev[8];
    #pragma unroll
    for (int j = 0; j < 8; ++j) ev[j] = esrc[csub + j * 4];

    // ---- 6. convert + MFMA (counted vmcnt lets MFMA start early) ----
    floatx4 acc[8];
    #pragma unroll
    for (int ct = 0; ct < 8; ++ct) acc[ct] = (floatx4){0.f, 0.f, 0.f, 0.f};
    #pragma unroll
    for (int ks = 0; ks < 8; ++ks) {
        const float4 a0 = av[2 * ks];
        const float4 a1 = av[2 * ks + 1];
        short8 af;
        af[0] = (short)f2bf(a0.x); af[1] = (short)f2bf(a0.y);
        af[2] = (short)f2bf(a0.z); af[3] = (short)f2bf(a0.w);
        af[4] = (short)f2bf(a1.x); af[5] = (short)f2bf(a1.y);
        af[6] = (short)f2bf(a1.z); af[7] = (short)f2bf(a1.w);
        #pragma unroll
        for (int ct = 0; ct < 8; ++ct)
            acc[ct] = __builtin_amdgcn_mfma_f32_16x16x32_bf16(
                af, sB[(ct * 8 + ks) * 64 + l], acc[ct], 0, 0, 0);
    }

    // ---- 7. store projected rows (D: row = kg*4+r, col = ct*16+lr) ----
    #pragma unroll
    for (int r = 0; r < 4; ++r) {
        const int row = kg * 4 + r;
        const int t_r = __shfl(tid, row);
        const long long node = nodebase + row;
        if (t_r == 0 && node < n) {
            float* orow = out + node * DOUT;
            #pragma unroll
            for (int ct = 0; ct < 8; ++ct)
                orow[ct * 16 + lr] = acc[ct][r];
        }
    }

    // ---- 8. featureless-row stores (loads long since landed) ----
    if (copyrow) {
        float4* dst = reinterpret_cast<float4*>(out + cnode * DOUT);
        #pragma unroll
        for (int j = 0; j < 8; ++j) dst[csub + j * 4] = ev[j];
    }
}

extern "C" void kernel_launch(void* const* d_in, const int* in_sizes, int n_in,
                              void* d_out, int out_size, void* d_ws, size_t ws_size,
                              hipStream_t stream) {
    const float* feat0      = (const float*)d_in[0];
    const float* W0         = (const float*)d_in[1];
    const float* emb_table  = (const float*)d_in[2];
    const int*   node_ids   = (const int*)d_in[3];
    const int*   node_tids  = (const int*)d_in[4];
    const int*   type_ids   = (const int*)d_in[5];
    float*       out        = (float*)d_out;
    const int n = in_sizes[3];                      // N = 500000

    unsigned short* Bfrag = (unsigned short*)d_ws;  // 64 KB in workspace

    hipLaunchKernelGGL(w0_pack_kernel, dim3((DIN * DOUT) / 256), dim3(256),
                       0, stream, W0, Bfrag);

    const int grid = (n + 127) / 128;               // 128 nodes per block
    hipLaunchKernelGGL(fused_embed_kernel, dim3(grid), dim3(512), 0, stream,
                       feat0, emb_table, Bfrag, node_ids, node_tids, type_ids,
                       out, n);
}